// Round 8
// baseline (921.346 us; speedup 1.0000x reference)
//
#include <hip/hip_runtime.h>
#include <math.h>

// Problem constants
#define NB  262144   // batch
#define SD  128      // STATE_DIM
#define HID 256      // HIDDEN
#define AD  8        // ACTION_DIM

typedef float v2f __attribute__((ext_vector_type(2)));

// d_ws layout (floats)
#define W1T_OFF 0                       // [SD][HID]   W1T[k*HID+j] = W1[j*SD+k]
#define W2T_OFF (SD*HID)                // [HID][HID]  32768
#define W3P_OFF (W2T_OFF + HID*HID)     // [HID][AD] float2 pairs (u,s): 98304, 4096 floats
#define B1_OFF  (W3P_OFF + HID*2*AD)    // 102400
#define B2_OFF  (B1_OFF + HID)          // 102656
#define B3P_OFF (B2_OFF + HID)          // 102912, [AD] float2 pairs
#define WS_FLOATS (B3P_OFF + 2*AD)      // 102928 floats = 411,712 bytes

__global__ __launch_bounds__(256) void prep_weights(
    const float* __restrict__ W1, const float* __restrict__ b1,
    const float* __restrict__ W2, const float* __restrict__ b2,
    const float* __restrict__ W3, const float* __restrict__ b3,
    float* __restrict__ ws) {
  int stride = gridDim.x * blockDim.x;
  for (int i = blockIdx.x * blockDim.x + threadIdx.x; i < WS_FLOATS; i += stride) {
    float v;
    if (i < W2T_OFF) {                       // W1T
      int k = i >> 8, j = i & 255;
      v = W1[j * SD + k];
    } else if (i < W3P_OFF) {                // W2T
      int t = i - W2T_OFF;
      int k = t >> 8, j = t & 255;
      v = W2[j * HID + k];
    } else if (i < B1_OFF) {                 // W3P[k][a] = (W3[a][k], W3[a+8][k])
      int t = i - W3P_OFF;
      int k = t >> 4, a = (t >> 1) & 7, h = t & 1;
      v = W3[(a + 8 * h) * HID + k];
    } else if (i < B2_OFF) {
      v = b1[i - B1_OFF];
    } else if (i < B3P_OFF) {
      v = b2[i - B2_OFF];
    } else {                                 // B3P[a] = (b3[a], b3[a+8])
      int t = i - B3P_OFF;
      v = b3[(t >> 1) + 8 * (t & 1)];
    }
    ws[i] = v;
  }
}

// R12 theory: across R4..R11 the ONLY monotone correlate of dur is the count
// of wave-uniform LDS broadcast reads in the inner loop:
//   R6 halve VALU instrs -> 0 change | R7/R8 occupancy -> 0 change |
//   R9 halve L2 weight bytes but 2x broadcast reads -> +57 us |
//   R11 halve HBM fetch but +256 broadcast reads/wave -> +38 us.
// A broadcast ds_read_b128 delivers 16 unique bytes yet occupies the
// CU-shared LDS pipe and puts a ~120-cyc lgkmcnt round-trip in every
// k-iteration's dependency chain. Fix: layer-2 h1 broadcast via v_readlane
// (VALU->SGPR, reg indices static, lane index SGPR-uniform), h1 never
// leaves registers; layer-1 x stays on the global-uniform VMEM path (R8,
// proven cheaper than LDS); LDS remains only for layer-3's transpose.
// Paid from the measured 40% VALU idle: +32 readlane per 128 fmac.
__global__ __launch_bounds__(128, 4) void actor_fused(
    const float* __restrict__ state, const float* __restrict__ eps,
    const float* __restrict__ ws, int* __restrict__ out) {
  __shared__ float s_h[16][256];   // 16,384 B; used ONLY for h2 (layer 3)

  const int tid  = threadIdx.x;
  const int lane = tid & 63;
  const int wvu  = __builtin_amdgcn_readfirstlane(tid >> 6);  // 0..1, uniform
  const long wrow = (long)blockIdx.x * 16 + wvu * 8;          // wave's first row

  const float4* __restrict__ W1T4 = (const float4*)(ws + W1T_OFF);  // [SD][64]
  const float4* __restrict__ W2T4 = (const float4*)(ws + W2T_OFF);  // [HID][64]
  const v2f*    __restrict__ W3P  = (const v2f*)(ws + W3P_OFF);     // [HID][8]

  const float* __restrict__ xbase = state + wrow * SD;   // uniform pointer

  // ---- layer 1: h1 = relu(x @ W1^T + b1), K = 128  (R8-identical)
  float acc[8][4];
  #pragma unroll
  for (int r = 0; r < 8; ++r)
    #pragma unroll
    for (int c = 0; c < 4; ++c) acc[r][c] = 0.0f;

  #pragma unroll 2
  for (int k0 = 0; k0 < SD; k0 += 4) {
    float4 w[4];
    #pragma unroll
    for (int j = 0; j < 4; ++j) w[j] = W1T4[(k0 + j) * 64 + lane];
    float4 xv[8];
    #pragma unroll
    for (int r = 0; r < 8; ++r)                       // uniform address: one line
      xv[r] = *(const float4*)(xbase + r * SD + k0);  // serves the whole wave
    #pragma unroll
    for (int j = 0; j < 4; ++j) {
      #pragma unroll
      for (int r = 0; r < 8; ++r) {
        float x = (j == 0) ? xv[r].x : (j == 1) ? xv[r].y
                : (j == 2) ? xv[r].z : xv[r].w;
        acc[r][0] = fmaf(x, w[j].x, acc[r][0]);
        acc[r][1] = fmaf(x, w[j].y, acc[r][1]);
        acc[r][2] = fmaf(x, w[j].z, acc[r][2]);
        acc[r][3] = fmaf(x, w[j].w, acc[r][3]);
      }
    }
  }

  // bias + relu -> REGISTERS (h1 never touches LDS)
  float h1r[8][4];
  {
    float4 bb = ((const float4*)(ws + B1_OFF))[lane];
    #pragma unroll
    for (int r = 0; r < 8; ++r) {
      float v0 = acc[r][0] + bb.x, v1 = acc[r][1] + bb.y;
      float v2 = acc[r][2] + bb.z, v3 = acc[r][3] + bb.w;
      h1r[r][0] = v0 > 0.0f ? v0 : 0.0f;
      h1r[r][1] = v1 > 0.0f ? v1 : 0.0f;
      h1r[r][2] = v2 > 0.0f ? v2 : 0.0f;
      h1r[r][3] = v3 > 0.0f ? v3 : 0.0f;
    }
  }

  // ---- layer 2: h2 = relu(h1 @ W2^T + b2), K = 256.
  // h1[r][k0+j] lives in lane (k0>>2), component j -> v_readlane broadcast.
  // All h-path latency is VALU forwarding; zero LDS in this loop.
  #pragma unroll
  for (int r = 0; r < 8; ++r)
    #pragma unroll
    for (int c = 0; c < 4; ++c) acc[r][c] = 0.0f;

  #pragma unroll 2
  for (int k0 = 0; k0 < HID; k0 += 4) {
    const int srcl = k0 >> 2;            // owning lane, wave-uniform (SGPR)
    float4 w[4];
    #pragma unroll
    for (int j = 0; j < 4; ++j) w[j] = W2T4[(k0 + j) * 64 + lane];
    #pragma unroll
    for (int j = 0; j < 4; ++j) {
      float xs[8];
      #pragma unroll
      for (int r = 0; r < 8; ++r)
        xs[r] = __int_as_float(
            __builtin_amdgcn_readlane(__float_as_int(h1r[r][j]), srcl));
      #pragma unroll
      for (int r = 0; r < 8; ++r) {
        acc[r][0] = fmaf(xs[r], w[j].x, acc[r][0]);
        acc[r][1] = fmaf(xs[r], w[j].y, acc[r][1]);
        acc[r][2] = fmaf(xs[r], w[j].z, acc[r][2]);
        acc[r][3] = fmaf(xs[r], w[j].w, acc[r][3]);
      }
    }
  }

  // bias + relu -> h2 into wave-private LDS rows (layer-3 transpose source);
  // float4-group g stored at (g ^ r). No barrier: rows are wave-private.
  {
    float4 bb = ((const float4*)(ws + B2_OFF))[lane];
    #pragma unroll
    for (int r = 0; r < 8; ++r) {
      float4 hv;
      hv.x = acc[r][0] + bb.x; hv.y = acc[r][1] + bb.y;
      hv.z = acc[r][2] + bb.z; hv.w = acc[r][3] + bb.w;
      hv.x = hv.x > 0.0f ? hv.x : 0.0f;
      hv.y = hv.y > 0.0f ? hv.y : 0.0f;
      hv.z = hv.z > 0.0f ? hv.z : 0.0f;
      hv.w = hv.w > 0.0f ? hv.w : 0.0f;
      *(float4*)&s_h[wvu * 8 + r][(lane ^ r) << 2] = hv;
    }
  }

  // ---- layer 3 (K=256, N=16) + epilogue. Lane -> (row = lane>>3, action = lane&7),
  // both u and s chains serial k-ascending (matches sgemm).
  {
    const int r3 = lane >> 3;
    const int a  = lane & 7;
    const float* __restrict__ h2row = &s_h[wvu * 8 + r3][0];
    float accu = 0.0f, accs = 0.0f;
    #pragma unroll 2
    for (int k0 = 0; k0 < HID; k0 += 4) {
      const int col = ((k0 >> 2) ^ r3) << 2;          // XOR layout; 8 rows -> 8 banks
      v2f ha = *(const v2f*)(h2row + col);            // k0, k0+1 (8-lane broadcast)
      v2f hb = *(const v2f*)(h2row + col + 2);        // k0+2, k0+3
      v2f wp0 = W3P[(k0 + 0) * 8 + a];
      v2f wp1 = W3P[(k0 + 1) * 8 + a];
      v2f wp2 = W3P[(k0 + 2) * 8 + a];
      v2f wp3 = W3P[(k0 + 3) * 8 + a];
      accu = fmaf(ha.x, wp0.x, accu); accs = fmaf(ha.x, wp0.y, accs);
      accu = fmaf(ha.y, wp1.x, accu); accs = fmaf(ha.y, wp1.y, accs);
      accu = fmaf(hb.x, wp2.x, accu); accs = fmaf(hb.x, wp2.y, accs);
      accu = fmaf(hb.y, wp3.x, accu); accs = fmaf(hb.y, wp3.y, accs);
    }
    v2f b3p = ((const v2f*)(ws + B3P_OFF))[a];
    float nu = accu + b3p.x;
    float ns = accs + b3p.y;

    long grow = wrow + r3;
    float sa = fabsf(ns);
    float ev = eps[grow * AD + a];                // coalesced: base + lane
    float t  = __fmul_rn(sa, ev);                 // separately-rounded mul
    float z  = __fadd_rn(nu, t);                  // separately-rounded add
    float e  = (float)exp(-(double)z);            // correctly-rounded expf near boundary
    float d  = __fadd_rn(1.0f, e);
    float act = 1.0f / d;
    float q  = act * 8.0f;                        // exact
    float wq = __fadd_rn(q, 1.0f);
    out[grow * AD + a] = (int)wq;                 // truncation, as astype(int32)
  }
}

extern "C" void kernel_launch(void* const* d_in, const int* in_sizes, int n_in,
                              void* d_out, int out_size, void* d_ws, size_t ws_size,
                              hipStream_t stream) {
  const float* state = (const float*)d_in[0];
  const float* W1    = (const float*)d_in[1];
  const float* b1    = (const float*)d_in[2];
  const float* W2    = (const float*)d_in[3];
  const float* b2    = (const float*)d_in[4];
  const float* W3    = (const float*)d_in[5];
  const float* b3    = (const float*)d_in[6];
  const float* eps   = (const float*)d_in[7];
  int*   out = (int*)d_out;
  float* ws  = (float*)d_ws;   // 411,712 bytes; rebuilt every launch

  hipLaunchKernelGGL(prep_weights, dim3(128), dim3(256), 0, stream,
                     W1, b1, W2, b2, W3, b3, ws);
  hipLaunchKernelGGL(actor_fused, dim3(NB / 16), dim3(128), 0, stream,
                     state, eps, ws, out);
}